// Round 6
// baseline (149.106 us; speedup 1.0000x reference)
//
#include <hip/hip_runtime.h>

#define TT 3
#define CCH 32
#define HH 256
#define WW 256
#define KK 7
#define NQ 64
#define QPB 16
#define V1W 76            // y row length (qwi=15 reads dwords 60..75)
#define V1R 14
#define V1N (V1R*V1W)     // 1064 dwords per channel plane
#define V1P 1080          // padded plane stride (16B-aligned)
#define CHC 8             // channels per chunk
#define NCHUNK 4
#define BUFSZ (CHC * V1P) // dwords per LDS buffer
#define LDS_BYTES (2 * BUFSZ * 4)   // 69120 B

__device__ __forceinline__ int refl(int i, int n) {
    i = i < 0 ? -i : i;
    return i >= n ? 2*(n-1) - i : i;
}

__device__ __forceinline__ void gload_lds(const float* g, float* l) {
    __builtin_amdgcn_global_load_lds(
        (const __attribute__((address_space(1))) unsigned int*)g,
        (__attribute__((address_space(3))) unsigned int*)l, 4, 0, 0);
}

extern __shared__ float smem[];

__global__ __launch_bounds__(256, 2)
void nls_kernel(const float* __restrict__ vid0, const float* __restrict__ vid1,
                float* __restrict__ out) {
    float* v1s = smem;                 // two BUFSZ buffers

    const int bx  = blockIdx.x;
    const int t   = bx >> 8;
    const int rem = bx & 255;
    const int qy  = rem >> 2;
    const int q0  = (rem & 3) * QPB;
    const int qh  = qy * 4;
    const int w0  = 4*q0 - 7;

    const int tid   = threadIdx.x;
    const int qwi   = tid & 15;          // bits 0-3: query
    const int c01   = (tid >> 4) & 3;    // bits 4-5: channel low
    const int c2    = (tid >> 6) & 1;    // bit 6: channel high
    const int shh   = tid >> 7;          // bit 7: sh half
    const int clane = c01 + 4*c2;        // channel 0..7 within chunk
    const int qx    = q0 + qwi;

    // v1 staging offsets (channel-independent)
    int off1[5];
#pragma unroll
    for (int k = 0; k < 5; ++k) {
        int idx = tid + 256*k;
        if (idx < V1N) {
            int r = idx / V1W, wi = idx - r*V1W;
            off1[k] = refl(qh + r - 7, HH) * WW + refl(w0 + wi, WW);
        } else off1[k] = 0;
    }

    const float* g0t = vid0 + (size_t)t * (CCH*HH*WW);
    const float* g1t = vid1 + (size_t)t * (CCH*HH*WW);

    auto issue_dma = [&](int s, int buf) {
        float* base = v1s + buf * BUFSZ;
#pragma unroll
        for (int ch = 0; ch < CHC; ++ch) {
            const float* p1 = g1t + (size_t)(CHC*s + ch) * (HH*WW);
            float* lb = base + ch*V1P + (tid & ~63);
#pragma unroll
            for (int k = 0; k < 4; ++k)
                gload_lds(p1 + off1[k], lb + 256*k);
            if (tid < V1N - 1024)
                gload_lds(p1 + off1[4], base + ch*V1P + 1024 + (tid & ~63));
        }
    };

    float acc[4][8];
#pragma unroll
    for (int a = 0; a < 4; ++a)
#pragma unroll
        for (int b = 0; b < 8; ++b) acc[a][b] = 0.f;

    issue_dma(0, 0);                 // cold prefetch of chunk 0

#pragma unroll 1
    for (int s = 0; s < NCHUNK; ++s) {
        __syncthreads();   // drains DMA(s) — issued one full compute phase ago

        // ---- x patch loads FIRST (older than next DMA in vmcnt FIFO) ----
        const float* p0 = g0t + (size_t)(CHC*s + clane) * (HH*WW);
        float x[7][8];
#pragma unroll
        for (int i = 0; i < 7; ++i) {
            const float* rowp = p0 + refl(qh + i - 3, HH) * WW;
            float4 B = *(const float4*)(rowp + 4*qx);
            float4 A;
            if (qx > 0) A = *(const float4*)(rowp + 4*qx - 4);
            else        A = make_float4(0.f, B.w, B.z, B.y);   // reflect at w<0
            x[i][0]=A.y; x[i][1]=A.z; x[i][2]=A.w;
            x[i][3]=B.x; x[i][4]=B.y; x[i][5]=B.z; x[i][6]=B.w;
        }

        // ---- prefetch next chunk into the other buffer ----
        if (s + 1 < NCHUNK) issue_dma(s + 1, (s + 1) & 1);

        // ---- compute from buffer s&1: 4 sh x 8 sw per thread ----
        const float* yb = v1s + (s & 1) * BUFSZ + clane*V1P + 4*qwi;
#pragma unroll
        for (int rr = 0; rr < 10; ++rr) {
            const float* yp = yb + (4*shh + rr) * V1W;
            float4 Ya = ((const float4*)yp)[0];
            float4 Yb = ((const float4*)yp)[1];
            float4 Yc = ((const float4*)yp)[2];
            float4 Yd = ((const float4*)yp)[3];
            float y[16];
            y[0]=Ya.x;  y[1]=Ya.y;  y[2]=Ya.z;  y[3]=Ya.w;
            y[4]=Yb.x;  y[5]=Yb.y;  y[6]=Yb.z;  y[7]=Yb.w;
            y[8]=Yc.x;  y[9]=Yc.y;  y[10]=Yc.z; y[11]=Yc.w;
            y[12]=Yd.x; y[13]=Yd.y; y[14]=Yd.z; y[15]=Yd.w;
#pragma unroll
            for (int a = 0; a < 4; ++a) {
                const int pi = rr - a;              // compile-time after unroll
                if (pi >= 0 && pi < 7) {
#pragma unroll
                    for (int sw = 0; sw < 8; ++sw)
#pragma unroll
                        for (int j = 0; j < 7; ++j)
                            acc[a][sw] += x[pi][j] * y[sw + j];
                }
            }
        }
    }

    // ---- reduce over c01 (lane bits 4,5) ----
#pragma unroll
    for (int m = 16; m <= 32; m <<= 1)
#pragma unroll
        for (int a = 0; a < 4; ++a)
#pragma unroll
            for (int b = 0; b < 8; ++b)
                acc[a][b] += __shfl_xor(acc[a][b], m, 64);

    __syncthreads();                 // all LDS reads done; overlay dists
    float* dlds = v1s;               // [c2][16 q][64 shifts]
    if (c01 == 0) {
#pragma unroll
        for (int a = 0; a < 4; ++a) {
            float* dp = &dlds[c2*1024 + qwi*64 + (shh*4 + a)*8];
            *(float4*)(dp)     = make_float4(acc[a][0], acc[a][1], acc[a][2], acc[a][3]);
            *(float4*)(dp + 4) = make_float4(acc[a][4], acc[a][5], acc[a][6], acc[a][7]);
        }
    }
    __syncthreads();

    // ---- top-7: 16 threads per query ----
    {
        const int q16 = tid >> 4;
        const int l16 = tid & 15;
        const float* d0 = &dlds[q16 * 64];
        const float* d1 = d0 + 1024;
        const int j0 = l16 * 4;
        float cv[4];
#pragma unroll
        for (int jj = 0; jj < 4; ++jj) {
            float v = d0[j0 + jj] + d1[j0 + jj];
            if (j0 + jj == 36) v += 1e30f;    // self bias (selection only)
            cv[jj] = v;
        }
        unsigned mask = 0;
        const int qxx = q0 + q16;
        const int q   = (t*NQ + qy)*NQ + qxx;
        float* od = out + q*KK;
        float* oi = out + (size_t)TT*NQ*NQ*KK + (size_t)q*KK*3;
        for (int k = 0; k < KK; ++k) {
            float best = -3.4e38f; int bi = 1 << 30;
#pragma unroll
            for (int jj = 0; jj < 4; ++jj)
                if (!(mask & (1u << jj)) && cv[jj] > best) { best = cv[jj]; bi = j0 + jj; }
#pragma unroll
            for (int m = 1; m <= 8; m <<= 1) {
                float ob = __shfl_xor(best, m, 64);
                int  obi = __shfl_xor(bi,  m, 64);
                if (ob > best || (ob == best && obi < bi)) { best = ob; bi = obi; }
            }
            if ((bi >> 2) == l16) mask |= 1u << (bi & 3);
            if (l16 == 0) {
                od[k] = d0[bi] + d1[bi];       // unbiased value
                int dh = (bi >> 3) - 4;
                int dw = (bi & 7) - 4;
                oi[k*3 + 0] = (float)t;
                oi[k*3 + 1] = (float)refl(qh + dh, HH);
                oi[k*3 + 2] = (float)refl(qxx*4 + dw, WW);
            }
        }
    }
}

extern "C" void kernel_launch(void* const* d_in, const int* in_sizes, int n_in,
                              void* d_out, int out_size, void* d_ws, size_t ws_size,
                              hipStream_t stream) {
    (void)in_sizes; (void)n_in; (void)d_ws; (void)ws_size; (void)out_size;
    const float* vid0 = (const float*)d_in[0];
    const float* vid1 = (const float*)d_in[1];
    float* out = (float*)d_out;
    // Host-side attribute set (not a stream op — graph-capture safe). Needed
    // because 69120 B > 64 KB static LDS limit. Idempotent, done every call.
    (void)hipFuncSetAttribute((const void*)nls_kernel,
                              hipFuncAttributeMaxDynamicSharedMemorySize,
                              LDS_BYTES);
    nls_kernel<<<dim3(TT * NQ * (NQ / QPB)), dim3(256), LDS_BYTES, stream>>>(vid0, vid1, out);
}